// Round 1
// baseline (103.812 us; speedup 1.0000x reference)
//
#include <hip/hip_runtime.h>
#include <math.h>

#define BB 2048
#define NN 8192
#define HH 10
#define BETA 0.1f

__global__ __launch_bounds__(256) void frac_mlp_kernel(
    const float* __restrict__ y_plus,
    const int*   __restrict__ iidx,
    const float* __restrict__ DU,
    const float* __restrict__ Y,
    const float* __restrict__ aw1, const float* __restrict__ ab1,
    const float* __restrict__ aw2, const float* __restrict__ ab2,
    const float* __restrict__ w1,  const float* __restrict__ b1,
    const float* __restrict__ w2,  const float* __restrict__ b2,
    float* __restrict__ out)
{
    const int b   = blockIdx.x;
    const int tid = threadIdx.x;
    const int n   = iidx[b];
    const float yp = y_plus[b];

    // alpha = 1 - sigmoid(mlp(yp)) * (1 - exp(-beta*yp))   (all threads redundantly)
    float m = ab2[0];
    #pragma unroll
    for (int h = 0; h < HH; ++h)
        m += fmaxf(fmaf(yp, aw1[h], ab1[h]), 0.f) * aw2[h];
    const float g   = 1.f - expf(-BETA * yp);
    const float sig = 1.f / (1.f + expf(-m));
    const float a   = 1.f - sig * g;
    const float t   = 1.f - a;

    const float* yr = Y  + (size_t)b * NN;
    const float* dr = DU + (size_t)b * NN;
    const float yn = yr[n];

    double sm = 0.0;   // sum_main
    double tr = 0.0;   // trapezoid (only if a == 0)

    const bool need_main = (a != 0.f) && (a != 1.f) && (n >= 2);
    const bool need_trap = (a == 0.f) && (n >= 1);

    if (need_main) {
        const int kend = n - 2;                    // inclusive
        for (int k0 = tid * 4; k0 <= kend; k0 += 256 * 4) {
            float4 y4 = *reinterpret_cast<const float4*>(yr + k0);
            float4 d4 = *reinterpret_cast<const float4*>(dr + k0);
            // y[k0+4] needed only if element k0+3 is active (k0+4 <= kend+1 <= n-1 <= 8191)
            float ynext = (k0 + 4 <= kend + 1) ? yr[k0 + 4] : y4.w;
            float yv[5] = {y4.x, y4.y, y4.z, y4.w, ynext};
            float dv[4] = {d4.x, d4.y, d4.z, d4.w};
            float acc = 0.f;
            #pragma unroll
            for (int q = 0; q < 4; ++q) {
                int k = k0 + q;
                if (k <= kend) {
                    float p0 = powf(yn - yv[q],     t);
                    float p1 = powf(yn - yv[q + 1], t);
                    acc = fmaf(p0 - p1, dv[q], acc);
                }
            }
            sm += (double)acc;
        }
    }
    if (need_trap) {
        const int kend = n - 1;                    // inclusive segment index
        for (int k0 = tid * 4; k0 <= kend; k0 += 256 * 4) {
            float4 y4 = *reinterpret_cast<const float4*>(yr + k0);
            float4 d4 = *reinterpret_cast<const float4*>(dr + k0);
            float ynext = (k0 + 4 <= kend + 1) ? yr[k0 + 4] : y4.w;  // k0+4 <= n <= 8191
            float dnext = (k0 + 4 <= kend + 1) ? dr[k0 + 4] : d4.w;
            float yv[5] = {y4.x, y4.y, y4.z, y4.w, ynext};
            float dv[5] = {d4.x, d4.y, d4.z, d4.w, dnext};
            float acc = 0.f;
            #pragma unroll
            for (int q = 0; q < 4; ++q) {
                int k = k0 + q;
                if (k <= kend)
                    acc += (yv[q + 1] - yv[q]) * (dv[q + 1] + dv[q]) * 0.5f;
            }
            tr += (double)acc;
        }
    }

    // block reduction: wave64 shuffle, then LDS across the 4 waves
    for (int off = 32; off > 0; off >>= 1) {
        sm += __shfl_down(sm, off, 64);
        tr += __shfl_down(tr, off, 64);
    }
    __shared__ double s_sm[4], s_tr[4];
    const int wave = tid >> 6, lane = tid & 63;
    if (lane == 0) { s_sm[wave] = sm; s_tr[wave] = tr; }
    __syncthreads();

    if (tid == 0) {
        double smT = s_sm[0] + s_sm[1] + s_sm[2] + s_sm[3];
        double trT = s_tr[0] + s_tr[1] + s_tr[2] + s_tr[3];
        float dres;
        if (a == 0.f) {
            dres = (float)trT;
        } else if (a == 1.f) {
            dres = dr[n];
        } else if (n == 0) {
            dres = 0.f;
        } else {
            float last = powf(yn - yr[n - 1], t) * dr[n - 1];
            float fac  = expf(-lgammaf(2.f - a));
            dres = fac * ((float)smT + last);
        }
        float o = b2[0];
        #pragma unroll
        for (int h = 0; h < HH; ++h)
            o += fmaxf(fmaf(dres, w1[h], b1[h]), 0.f) * w2[h];
        out[b] = o;
    }
}

extern "C" void kernel_launch(void* const* d_in, const int* in_sizes, int n_in,
                              void* d_out, int out_size, void* d_ws, size_t ws_size,
                              hipStream_t stream) {
    const float* y_plus = (const float*)d_in[0];
    const int*   iidx   = (const int*)  d_in[1];
    const float* DU     = (const float*)d_in[2];
    const float* Y      = (const float*)d_in[3];
    const float* aw1    = (const float*)d_in[4];
    const float* ab1    = (const float*)d_in[5];
    const float* aw2    = (const float*)d_in[6];
    const float* ab2    = (const float*)d_in[7];
    const float* w1     = (const float*)d_in[8];
    const float* b1     = (const float*)d_in[9];
    const float* w2     = (const float*)d_in[10];
    const float* b2     = (const float*)d_in[11];
    float* out = (float*)d_out;

    frac_mlp_kernel<<<BB, 256, 0, stream>>>(y_plus, iidx, DU, Y,
                                            aw1, ab1, aw2, ab2,
                                            w1, b1, w2, b2, out);
}

// Round 2
// 18.725 us; speedup vs baseline: 5.5439x; 5.5439x over previous
//
#include <hip/hip_runtime.h>
#include <math.h>

#define BB 2048
#define NN 8192
#define HH 10
#define BETA 0.1f

// Hardware transcendentals: v_log_f32 = log2(x), v_exp_f32 = 2^x (~1 ulp each).
// Valid here since x = yn - y[k] > 0 for all active k (y strictly increasing).
__device__ __forceinline__ float fast_log2(float x) {
    float r; asm("v_log_f32 %0, %1" : "=v"(r) : "v"(x)); return r;
}
__device__ __forceinline__ float fast_exp2(float x) {
    float r; asm("v_exp_f32 %0, %1" : "=v"(r) : "v"(x)); return r;
}

__global__ __launch_bounds__(256) void frac_mlp_kernel(
    const float* __restrict__ y_plus,
    const int*   __restrict__ iidx,
    const float* __restrict__ DU,
    const float* __restrict__ Y,
    const float* __restrict__ aw1, const float* __restrict__ ab1,
    const float* __restrict__ aw2, const float* __restrict__ ab2,
    const float* __restrict__ w1,  const float* __restrict__ b1,
    const float* __restrict__ w2,  const float* __restrict__ b2,
    float* __restrict__ out)
{
    const int b   = blockIdx.x;
    const int tid = threadIdx.x;
    const int n   = iidx[b];
    const float yp = y_plus[b];

    // alpha = 1 - sigmoid(mlp(yp)) * (1 - exp(-beta*yp))   (all threads redundantly)
    float m = ab2[0];
    #pragma unroll
    for (int h = 0; h < HH; ++h)
        m += fmaxf(fmaf(yp, aw1[h], ab1[h]), 0.f) * aw2[h];
    const float g   = 1.f - expf(-BETA * yp);
    const float sig = 1.f / (1.f + expf(-m));
    const float a   = 1.f - sig * g;
    const float t   = 1.f - a;

    const float* yr = Y  + (size_t)b * NN;
    const float* dr = DU + (size_t)b * NN;
    const float yn = yr[n];

    double sm = 0.0;   // sum_main
    double tr = 0.0;   // trapezoid (only if a == 0)

    const bool need_main = (a != 0.f) && (a != 1.f) && (n >= 2);
    const bool need_trap = (a == 0.f) && (n >= 1);

    if (need_main) {
        const int kend = n - 2;                    // inclusive
        // 8-element chunks; telescoping: p1(k) = p0(k+1), so 9 pows per 8 terms.
        for (int k0 = tid * 8; k0 <= kend; k0 += 256 * 8) {
            float4 ya = *reinterpret_cast<const float4*>(yr + k0);
            float4 yb = *reinterpret_cast<const float4*>(yr + k0 + 4);
            float4 da = *reinterpret_cast<const float4*>(dr + k0);
            float4 db = *reinterpret_cast<const float4*>(dr + k0 + 4);
            // y[k0+8] needed only if element k0+7 active (then k0+8 <= n-1 <= 8191)
            float ynext = (k0 + 8 <= kend + 1) ? yr[k0 + 8] : yb.w;
            float yv[9] = {ya.x, ya.y, ya.z, ya.w, yb.x, yb.y, yb.z, yb.w, ynext};
            float dv[8] = {da.x, da.y, da.z, da.w, db.x, db.y, db.z, db.w};
            float p[9];
            #pragma unroll
            for (int j = 0; j < 9; ++j) {
                float x = fmaxf(yn - yv[j], 1e-30f);   // keep log argument positive
                p[j] = fast_exp2(t * fast_log2(x));
            }
            float acc = 0.f;
            #pragma unroll
            for (int q = 0; q < 8; ++q) {
                if (k0 + q <= kend)
                    acc = fmaf(p[q] - p[q + 1], dv[q], acc);
            }
            sm += (double)acc;
        }
    }
    if (need_trap) {
        const int kend = n - 1;                    // inclusive segment index
        for (int k0 = tid * 4; k0 <= kend; k0 += 256 * 4) {
            float4 y4 = *reinterpret_cast<const float4*>(yr + k0);
            float4 d4 = *reinterpret_cast<const float4*>(dr + k0);
            float ynext = (k0 + 4 <= kend + 1) ? yr[k0 + 4] : y4.w;  // k0+4 <= n <= 8191
            float dnext = (k0 + 4 <= kend + 1) ? dr[k0 + 4] : d4.w;
            float yv[5] = {y4.x, y4.y, y4.z, y4.w, ynext};
            float dv[5] = {d4.x, d4.y, d4.z, d4.w, dnext};
            float acc = 0.f;
            #pragma unroll
            for (int q = 0; q < 4; ++q) {
                int k = k0 + q;
                if (k <= kend)
                    acc += (yv[q + 1] - yv[q]) * (dv[q + 1] + dv[q]) * 0.5f;
            }
            tr += (double)acc;
        }
    }

    // block reduction: wave64 shuffle, then LDS across the 4 waves
    for (int off = 32; off > 0; off >>= 1) {
        sm += __shfl_down(sm, off, 64);
        tr += __shfl_down(tr, off, 64);
    }
    __shared__ double s_sm[4], s_tr[4];
    const int wave = tid >> 6, lane = tid & 63;
    if (lane == 0) { s_sm[wave] = sm; s_tr[wave] = tr; }
    __syncthreads();

    if (tid == 0) {
        double smT = s_sm[0] + s_sm[1] + s_sm[2] + s_sm[3];
        double trT = s_tr[0] + s_tr[1] + s_tr[2] + s_tr[3];
        float dres;
        if (a == 0.f) {
            dres = (float)trT;
        } else if (a == 1.f) {
            dres = dr[n];
        } else if (n == 0) {
            dres = 0.f;
        } else {
            float last = powf(yn - yr[n - 1], t) * dr[n - 1];  // once per row: exact powf
            float fac  = expf(-lgammaf(2.f - a));
            dres = fac * ((float)smT + last);
        }
        float o = b2[0];
        #pragma unroll
        for (int h = 0; h < HH; ++h)
            o += fmaxf(fmaf(dres, w1[h], b1[h]), 0.f) * w2[h];
        out[b] = o;
    }
}

extern "C" void kernel_launch(void* const* d_in, const int* in_sizes, int n_in,
                              void* d_out, int out_size, void* d_ws, size_t ws_size,
                              hipStream_t stream) {
    const float* y_plus = (const float*)d_in[0];
    const int*   iidx   = (const int*)  d_in[1];
    const float* DU     = (const float*)d_in[2];
    const float* Y      = (const float*)d_in[3];
    const float* aw1    = (const float*)d_in[4];
    const float* ab1    = (const float*)d_in[5];
    const float* aw2    = (const float*)d_in[6];
    const float* ab2    = (const float*)d_in[7];
    const float* w1     = (const float*)d_in[8];
    const float* b1     = (const float*)d_in[9];
    const float* w2     = (const float*)d_in[10];
    const float* b2     = (const float*)d_in[11];
    float* out = (float*)d_out;

    frac_mlp_kernel<<<BB, 256, 0, stream>>>(y_plus, iidx, DU, Y,
                                            aw1, ab1, aw2, ab2,
                                            w1, b1, w2, b2, out);
}